// Round 13
// baseline (24626.131 us; speedup 1.0000x reference)
//
#include <hip/hip_runtime.h>
#include <hip/hip_cooperative_groups.h>

#define B_ 64
#define H_ 1024
#define IN_ 512
#define S_ 256
#define L_ 6
#define NG_ 4096
#define NWG 192
#define NTICK (S_ + L_ - 1)

typedef __bf16 bf16x8 __attribute__((ext_vector_type(8)));
typedef float f32x4 __attribute__((ext_vector_type(4)));
typedef unsigned short ushort8v __attribute__((ext_vector_type(8)));
typedef unsigned short ushort_t;

// ws layout (bytes)
#define WP_BYTES 96468992ul
#define XB_BYTES 16777216ul
#define HBF_BYTES 1572864ul        // 2*6*65536*2
#define BIASP_BYTES 98304ul        // 6*1024*4 f32
#define FLAGS_BYTES 1024ul         // 96 ints padded
#define ZU_BYTES 3145728ul         // 96 * 32KB bf16 partials
#define LSLOT 65536ul              // packed h per layer (elems)
#define XSLOT 32768ul              // packed x per timestep (elems)

// W panel per (l,jb): unit (c*4 + nf*2 + ks) of 512 ushorts (1KB)
__host__ __device__ __forceinline__ size_t poff(int l, int jb) {
  return (l == 0) ? (size_t)jb * 49152ul
                  : 6291456ul + ((size_t)(l - 1) * 128 + jb) * 65536ul;
}

#define MFMA16(a, b, c) __builtin_amdgcn_mfma_f32_16x16x32_bf16(a, b, c, 0, 0, 0)
#define WAITN(n) asm volatile("s_waitcnt vmcnt(" #n ")" ::: "memory")

__device__ __forceinline__ unsigned short f2bf(float f) {
  union { float f; unsigned u; } v; v.f = f;
  unsigned r = v.u + 0x7fffu + ((v.u >> 16) & 1u);
  return (unsigned short)(r >> 16);
}
__device__ __forceinline__ float bfbits2f(unsigned short u) {
  union { unsigned u32; float f; } v; v.u32 = ((unsigned)u) << 16; return v.f;
}
__device__ __forceinline__ void gload_lds(const ushort_t* g, ushort_t* l) {
  __builtin_amdgcn_global_load_lds(
      (const __attribute__((address_space(1))) unsigned int*)g,
      (__attribute__((address_space(3))) unsigned int*)l, 16, 0, 0);
}

// ---- one-time weight pack (R12 layout, proven) ----
__global__ void k_pack_w(const float* __restrict__ U0, const float* __restrict__ V0,
                         const float* __restrict__ U, const float* __restrict__ V,
                         ushort_t* __restrict__ Wp) {
  const int bx = blockIdx.x;              // 0..767
  const int l = bx >> 7, jb = bx & 127;
  ushort_t* __restrict__ panel = Wp + poff(l, jb);
  const int KU = (l == 0) ? IN_ : H_;
  const int NU = KU >> 6;
  const int NCH = NU + 16;
  const float* __restrict__ Usrc = (l == 0) ? U0 : U + (size_t)(l - 1) * H_ * NG_;
  const float* __restrict__ Vsrc = (l == 0) ? V0 : V + (size_t)(l - 1) * H_ * NG_;
  const int t = threadIdx.x, lane = t & 63, g4 = t >> 6;
  const int l15 = lane & 15, kg = lane >> 4;
  for (int p = 0; p < NCH; ++p) {
    const int gi = p * 4 + g4;
    const int c = gi >> 2, u = gi & 3, nf = u >> 1, ks = u & 1;
    const int n = (nf * 2 + (l15 >> 3)) * 1024 + jb * 8 + (l15 & 7);
    const int k = c * 64 + ks * 32 + kg * 8;
    const float* __restrict__ src =
        (c < NU) ? (Usrc + (size_t)k * NG_ + n)
                 : (Vsrc + (size_t)(k - KU) * NG_ + n);
    ushort8v uv;
#pragma unroll
    for (int e = 0; e < 8; ++e) uv[e] = f2bf(src[(size_t)e * NG_]);
    *(ushort8v*)(panel + (size_t)gi * 512 + lane * 8) = uv;
  }
}

// ---- one-time x -> bf16, A-unit order u = c*8 + ks*4 + m ----
__global__ void k_cvt_x(const float* __restrict__ x, ushort_t* __restrict__ xb) {
  const int tt = blockIdx.x;
  const int tid = threadIdx.x;
  const int ln = tid & 63, grp = tid >> 6;   // 4 groups
  ushort_t* __restrict__ dst = xb + (size_t)tt * XSLOT;
  for (int u = grp; u < 64; u += 4) {
    const int c = u >> 3, ks = (u & 7) >> 2, m = u & 3;
    const int row = m * 16 + (ln & 15);
    const int k = c * 64 + ks * 32 + (ln >> 4) * 8;
    const float* __restrict__ src = x + ((size_t)row * S_ + tt) * IN_ + k;
    float4 v0 = *(const float4*)(src);
    float4 v1 = *(const float4*)(src + 4);
    ushort8v uv = { f2bf(v0.x), f2bf(v0.y), f2bf(v0.z), f2bf(v0.w),
                    f2bf(v1.x), f2bf(v1.y), f2bf(v1.z), f2bf(v1.w) };
    *(ushort8v*)(dst + (size_t)u * 512 + ln * 8) = uv;
  }
}

// ---- one-time bias repack: biasp[l][h][4] ----
__global__ void k_pack_bias(const float* __restrict__ b0, const float* __restrict__ bL,
                            float* __restrict__ biasp) {
  int i = blockIdx.x * 256 + threadIdx.x;
  if (i < 6144) {
    int l = i >> 10, h = i & 1023;
    const float* src = (l == 0) ? b0 : bL + (size_t)(l - 1) * NG_;
#pragma unroll
    for (int g = 0; g < 4; ++g) biasp[(size_t)i * 4 + g] = src[g * 1024 + h];
  }
}

// ============ persistent-weight cell body ============
template<int NC, bool ISV>
__device__ __forceinline__ void body(
    cooperative_groups::grid_group& grid, int l, int cg, int coff,
    const ushort_t* __restrict__ xb, const ushort_t* __restrict__ Wp,
    const float* __restrict__ biasp, ushort_t* __restrict__ hbf,
    int* __restrict__ flags, ushort_t* __restrict__ zu,
    float* __restrict__ out, ushort_t* ring, ushort_t* hst) {
  float* __restrict__ seq = out;
  float* __restrict__ hf = out + (size_t)B_ * S_ * H_;
  float* __restrict__ cf = hf + (size_t)L_ * B_ * H_;
  ushort_t* zlds = ring;                  // 32KB alias over ring[0..1]

  const int tid = threadIdx.x;
  const int wv = tid >> 6, lane = tid & 63;
  const int l15 = lane & 15, kg = lane >> 4;
  const int gp = wv >> 3, hs = wv & 7;
  const int jb = cg * 8 + hs;

  // ---- resident weights: 16 N-cols x NC*64 K per wave ----
  bf16x8 Wreg[NC][2];
  {
    const ushort_t* pb = Wp + poff(l, jb) + (size_t)coff * 2048;
#pragma unroll
    for (int c = 0; c < NC; ++c)
#pragma unroll
      for (int ks = 0; ks < 2; ++ks)
        Wreg[c][ks] = *(const bf16x8*)(pb + (size_t)(c * 4 + gp * 2 + ks) * 512 + lane * 8);
  }

  const int fr = tid >> 4;                // fusion row 0..63
  const int fh0 = (tid & 15) << 2;        // fusion hcl base
  float creg[4] = {0.f, 0.f, 0.f, 0.f};
  f32x4 breg[4];
  if (ISV) {
#pragma unroll
    for (int q = 0; q < 4; ++q)
      breg[q] = *(const f32x4*)(biasp + ((size_t)l * 1024 + cg * 64 + fh0 + q) * 4);
  }
  const int fidx = l * 16 + cg;
  constexpr int NCH2 = NC / 2;

  for (int T = 0; T < NTICK; ++T) {
    const int t = T - l;
    if (t >= 0 && t < S_) {
      const ushort_t* Ab;
      if (!ISV && l == 0) Ab = xb + (size_t)t * XSLOT;
      else {
        const int lA = ISV ? l : (l - 1);
        Ab = hbf + (size_t)((T + 1) & 1) * (L_ * LSLOT) + (size_t)lA * LSLOT;
      }
      ushort_t* hcur = hbf + (size_t)(T & 1) * (L_ * LSLOT) + (size_t)l * LSLOT;

      f32x4 acc[4];
#pragma unroll
      for (int m = 0; m < 4; ++m) acc[m] = (f32x4){0.f, 0.f, 0.f, 0.f};

#define STAGE(j) gload_lds(Ab + (size_t)(j) * 8192 + wv * 512 + lane * 8, \
                           ring + ((j) % 3) * 8192 + wv * 512)
      STAGE(0); STAGE(1);
#pragma unroll
      for (int j = 0; j < NCH2; ++j) {
        if (j + 1 < NCH2) { WAITN(1); } else { WAITN(0); }
        __builtin_amdgcn_s_barrier();
        if (j + 2 < NCH2) STAGE(j + 2);
        const ushort_t* rb = ring + (j % 3) * 8192;
#pragma unroll
        for (int cc = 0; cc < 2; ++cc)
#pragma unroll
          for (int ks = 0; ks < 2; ++ks) {
            const int base = (cc * 8 + ks * 4) * 512 + lane * 8;
            bf16x8 A0 = *(const bf16x8*)(rb + base);
            bf16x8 A1 = *(const bf16x8*)(rb + base + 512);
            bf16x8 A2 = *(const bf16x8*)(rb + base + 1024);
            bf16x8 A3 = *(const bf16x8*)(rb + base + 1536);
            acc[0] = MFMA16(A0, Wreg[j * 2 + cc][ks], acc[0]);
            acc[1] = MFMA16(A1, Wreg[j * 2 + cc][ks], acc[1]);
            acc[2] = MFMA16(A2, Wreg[j * 2 + cc][ks], acc[2]);
            acc[3] = MFMA16(A3, Wreg[j * 2 + cc][ks], acc[3]);
          }
      }
#undef STAGE
      __syncthreads();                    // ring reads done; zlds alias safe
#pragma unroll
      for (int m = 0; m < 4; ++m)
#pragma unroll
        for (int jj = 0; jj < 4; ++jj)
          zlds[wv * 1024 + (m * 16 + kg * 4 + jj) * 16 + l15] = f2bf(acc[m][jj]);
      __syncthreads();

      ushort_t* slot = zu + (size_t)fidx * 16384;
      if (!ISV) {
        // assemble per-(row,hcol) gate quads, publish partial + flag
#pragma unroll
        for (int q = 0; q < 4; ++q) {
          const int hcl = fh0 + q;
          const int fb = (hcl >> 3) * 1024 + fr * 16 + (hcl & 7);
          unsigned v01 = (unsigned)zlds[fb] | ((unsigned)zlds[fb + 8] << 16);
          unsigned v23 = (unsigned)zlds[8 * 1024 + fb] | ((unsigned)zlds[8 * 1024 + fb + 8] << 16);
          *(uint2*)(slot + ((size_t)fr * 64 + hcl) * 4) = make_uint2(v01, v23);
        }
        __threadfence();
        __syncthreads();
        if (tid == 0)
          __hip_atomic_store(&flags[fidx], t + 1, __ATOMIC_RELEASE, __HIP_MEMORY_SCOPE_AGENT);
      } else {
        if (tid == 0) {
          while (__hip_atomic_load(&flags[fidx], __ATOMIC_ACQUIRE,
                                   __HIP_MEMORY_SCOPE_AGENT) < t + 1)
            __builtin_amdgcn_s_sleep(2);
        }
        __syncthreads();
#pragma unroll
        for (int q = 0; q < 4; ++q) {
          const int hcl = fh0 + q;
          const int fb = (hcl >> 3) * 1024 + fr * 16 + (hcl & 7);
          float zv0 = bfbits2f(zlds[fb]);
          float zv1 = bfbits2f(zlds[fb + 8]);
          float zv2 = bfbits2f(zlds[8 * 1024 + fb]);
          float zv3 = bfbits2f(zlds[8 * 1024 + fb + 8]);
          unsigned long long up = __hip_atomic_load(
              (const unsigned long long*)(slot + ((size_t)fr * 64 + hcl) * 4),
              __ATOMIC_RELAXED, __HIP_MEMORY_SCOPE_AGENT);
          float zi = zv0 + bfbits2f((unsigned short)up) + breg[q][0];
          float zf = zv1 + bfbits2f((unsigned short)(up >> 16)) + breg[q][1];
          float zg = zv2 + bfbits2f((unsigned short)(up >> 32)) + breg[q][2];
          float zo = zv3 + bfbits2f((unsigned short)(up >> 48)) + breg[q][3];
          float iv = 1.f / (1.f + expf(-zi));
          float fv = 1.f / (1.f + expf(-zf));
          float gv = tanhf(zg);
          float ov = 1.f / (1.f + expf(-zo));
          float cn = fv * creg[q] + iv * gv;
          creg[q] = cn;
          float hv = ov * tanhf(cn);
          hst[fr * 64 + hcl] = f2bf(hv);
          const int hc = cg * 64 + hcl;
          if (l == L_ - 1) seq[((size_t)fr * S_ + t) * H_ + hc] = hv;
          if (t == S_ - 1) {
            cf[((size_t)l * B_ + fr) * H_ + hc] = cn;
            hf[((size_t)l * B_ + fr) * H_ + hc] = hv;
          }
        }
        __syncthreads();
        if (tid < 512) {                  // write h in packed A-unit order
          const int u = tid >> 6, ln = tid & 63;
          const int m = u & 3, ks = u >> 2;
          ushort8v v = *(const ushort8v*)(hst + (m * 16 + (ln & 15)) * 64 +
                                          ks * 32 + (ln >> 4) * 8);
          *(ushort8v*)(hcur + ((size_t)cg * 8 + u) * 512 + ln * 8) = v;
        }
      }
    }
    grid.sync();
  }
}

__global__ void __launch_bounds__(1024, 1)
k_lstm(const ushort_t* __restrict__ xb, const ushort_t* __restrict__ Wp,
       const float* __restrict__ biasp, ushort_t* __restrict__ hbf,
       int* __restrict__ flags, ushort_t* __restrict__ zu,
       float* __restrict__ out) {
  cooperative_groups::grid_group grid = cooperative_groups::this_grid();
  __shared__ __align__(16) ushort_t ring[3 * 8192];   // 48 KB
  __shared__ __align__(16) ushort_t hst[4096];        // 8 KB
  const int wg = blockIdx.x;
  const int l = wg >> 5, rr = wg & 31, role = rr >> 4, cg = rr & 15;
  if (role == 0) {
    if (l == 0)
      body<8, false>(grid, l, cg, 0, xb, Wp, biasp, hbf, flags, zu, out, ring, hst);
    else
      body<16, false>(grid, l, cg, 0, xb, Wp, biasp, hbf, flags, zu, out, ring, hst);
  } else {
    body<16, true>(grid, l, cg, (l == 0) ? 8 : 16, xb, Wp, biasp, hbf, flags, zu, out,
                   ring, hst);
  }
}

extern "C" void kernel_launch(void* const* d_in, const int* in_sizes, int n_in,
                              void* d_out, int out_size, void* d_ws, size_t ws_size,
                              hipStream_t stream) {
  const float* x = (const float*)d_in[0];
  const float* U0 = (const float*)d_in[1];
  const float* V0 = (const float*)d_in[2];
  const float* b0 = (const float*)d_in[3];
  const float* U = (const float*)d_in[4];
  const float* V = (const float*)d_in[5];
  const float* bL = (const float*)d_in[6];
  float* out = (float*)d_out;

  char* ws = (char*)d_ws;
  unsigned short* Wp = (unsigned short*)ws;
  unsigned short* xb = (unsigned short*)(ws + WP_BYTES);
  unsigned short* hbf = (unsigned short*)(ws + WP_BYTES + XB_BYTES);
  float* biasp = (float*)(ws + WP_BYTES + XB_BYTES + HBF_BYTES);
  int* flags = (int*)(ws + WP_BYTES + XB_BYTES + HBF_BYTES + BIASP_BYTES);
  unsigned short* zu = (unsigned short*)(ws + WP_BYTES + XB_BYTES + HBF_BYTES +
                                         BIASP_BYTES + FLAGS_BYTES);

  hipLaunchKernelGGL(k_pack_w, dim3(768), dim3(256), 0, stream, U0, V0, U, V, Wp);
  hipLaunchKernelGGL(k_cvt_x, dim3(S_), dim3(256), 0, stream, x, xb);
  hipLaunchKernelGGL(k_pack_bias, dim3(24), dim3(256), 0, stream, b0, bL, biasp);
  hipMemsetAsync(hbf, 0, HBF_BYTES, stream);
  hipMemsetAsync(flags, 0, FLAGS_BYTES, stream);

  void* args[] = { (void*)&xb, (void*)&Wp, (void*)&biasp, (void*)&hbf,
                   (void*)&flags, (void*)&zu, (void*)&out };
  hipLaunchCooperativeKernel((void*)k_lstm, dim3(NWG), dim3(1024), args, 0, stream);
}

// Round 14
// 13559.253 us; speedup vs baseline: 1.8162x; 1.8162x over previous
//
#include <hip/hip_runtime.h>
#include <hip/hip_cooperative_groups.h>

#define B_ 64
#define H_ 1024
#define IN_ 512
#define S_ 256
#define L_ 6
#define NG_ 4096
#define NTASK 768            // 6 cells * 128 col-slices (8 H-cols x 4 gates)
#define NTICK (S_ + L_ - 1)

typedef __bf16 bf16x8 __attribute__((ext_vector_type(8)));
typedef float f32x4 __attribute__((ext_vector_type(4)));
typedef float f32x2 __attribute__((ext_vector_type(2)));
typedef unsigned short ushort8v __attribute__((ext_vector_type(8)));
typedef unsigned short ushort_t;

#define WP_BYTES 96468992ul
#define XB_BYTES 16777216ul
#define HBF_ELEMS 786432ul          // 2 slots * L * 65536
#define LSLOT 65536ul               // packed h per layer (elems)
#define XSLOT 32768ul               // packed x per timestep (elems)

// W panel per (l,jb): unit (c*4 + nf*2 + ks) of 512 ushorts (1KB)
__host__ __device__ __forceinline__ size_t poff(int l, int jb) {
  return (l == 0) ? (size_t)jb * 49152ul
                  : 6291456ul + ((size_t)(l - 1) * 128 + jb) * 65536ul;
}

#define MFMA16(a, b, c) __builtin_amdgcn_mfma_f32_16x16x32_bf16(a, b, c, 0, 0, 0)
#define WAITN(n) asm volatile("s_waitcnt vmcnt(" #n ")" ::: "memory")
#define SB0() __builtin_amdgcn_sched_barrier(0)

__device__ __forceinline__ unsigned short f2bf(float f) {
  union { float f; unsigned u; } v; v.f = f;
  unsigned r = v.u + 0x7fffu + ((v.u >> 16) & 1u);
  return (unsigned short)(r >> 16);
}

// ---- one-time weight pack (proven layout) ----
__global__ void k_pack_w(const float* __restrict__ U0, const float* __restrict__ V0,
                         const float* __restrict__ U, const float* __restrict__ V,
                         ushort_t* __restrict__ Wp) {
  const int bx = blockIdx.x;              // 0..767
  const int l = bx >> 7, jb = bx & 127;
  ushort_t* __restrict__ panel = Wp + poff(l, jb);
  const int KU = (l == 0) ? IN_ : H_;
  const int NU = KU >> 6;
  const int NCH = NU + 16;
  const float* __restrict__ Usrc = (l == 0) ? U0 : U + (size_t)(l - 1) * H_ * NG_;
  const float* __restrict__ Vsrc = (l == 0) ? V0 : V + (size_t)(l - 1) * H_ * NG_;
  const int t = threadIdx.x, lane = t & 63, g4 = t >> 6;
  const int l15 = lane & 15, kg = lane >> 4;
  for (int p = 0; p < NCH; ++p) {
    const int gi = p * 4 + g4;
    const int c = gi >> 2, u = gi & 3, nf = u >> 1, ks = u & 1;
    const int n = (nf * 2 + (l15 >> 3)) * 1024 + jb * 8 + (l15 & 7);
    const int k = c * 64 + ks * 32 + kg * 8;
    const float* __restrict__ src =
        (c < NU) ? (Usrc + (size_t)k * NG_ + n)
                 : (Vsrc + (size_t)(k - KU) * NG_ + n);
    ushort8v uv;
#pragma unroll
    for (int e = 0; e < 8; ++e) uv[e] = f2bf(src[(size_t)e * NG_]);
    *(ushort8v*)(panel + (size_t)gi * 512 + lane * 8) = uv;
  }
}

// ---- one-time x -> bf16, packed-A unit order (c*8 + m*2 + ks) ----
__global__ void k_cvt_x(const float* __restrict__ x, ushort_t* __restrict__ xb) {
  const int tt = blockIdx.x;
  const int tid = threadIdx.x;
  const int b = tid >> 2, kq = (tid & 3) << 7;
  const float* __restrict__ src = x + ((size_t)b * S_ + tt) * IN_ + kq;
  ushort_t* __restrict__ dst = xb + (size_t)tt * XSLOT;
  const int m = b >> 4, l15 = b & 15;
#pragma unroll
  for (int kk = 0; kk < 128; kk += 8) {
    float4 v0 = *(const float4*)(src + kk);
    float4 v1 = *(const float4*)(src + kk + 4);
    ushort8v u = { f2bf(v0.x), f2bf(v0.y), f2bf(v0.z), f2bf(v0.w),
                   f2bf(v1.x), f2bf(v1.y), f2bf(v1.z), f2bf(v1.w) };
    const int k = kq + kk;
    const int c = k >> 6, ksl = (k >> 5) & 1, kg = (k & 31) >> 3;
    *(ushort8v*)(dst + (((size_t)c * 8 + m * 2 + ksl) * 64 + kg * 16 + l15) * 8) = u;
  }
}

// Per-wave K-quarter GEMM: ALL 64 rows x 32 N-cols over Q=NCH/4 chunks.
// acc[m][nf]; depth-2 bank pipeline (12 loads/chunk).
template<int NCH>
__device__ __forceinline__ void gemm_q(f32x4 acc[4][2],
                                       const ushort_t* __restrict__ panel,
                                       const ushort_t* __restrict__ A1,
                                       const ushort_t* __restrict__ A2,
                                       int w, int lane) {
  constexpr int NU = NCH - 16;
  constexpr int Q = NCH / 4;
  bf16x8 Wb[2][4];
  bf16x8 Ab[2][8];
#define LDU(p) (*(const bf16x8*)(p))
#define ISSUE(c, bk) do { \
    const ushort_t* wp_ = panel + (size_t)(c) * 2048 + lane * 8; \
    Wb[bk][0] = LDU(wp_); \
    Wb[bk][1] = LDU(wp_ + 512); \
    Wb[bk][2] = LDU(wp_ + 1024); \
    Wb[bk][3] = LDU(wp_ + 1536); \
    const ushort_t* ap_ = ((c) < NU \
        ? A1 + (size_t)(c) * 4096 : A2 + (size_t)((c) - NU) * 4096) + lane * 8; \
    Ab[bk][0] = LDU(ap_); \
    Ab[bk][1] = LDU(ap_ + 512); \
    Ab[bk][2] = LDU(ap_ + 1024); \
    Ab[bk][3] = LDU(ap_ + 1536); \
    Ab[bk][4] = LDU(ap_ + 2048); \
    Ab[bk][5] = LDU(ap_ + 2560); \
    Ab[bk][6] = LDU(ap_ + 3072); \
    Ab[bk][7] = LDU(ap_ + 3584); \
  } while (0)
  const int c0 = w * Q;
  ISSUE(c0, 0);
  if (Q > 1) ISSUE(c0 + 1, 1);
  SB0();
#pragma unroll
  for (int j = 0; j < Q; ++j) {
    if (j + 1 < Q) { WAITN(12); } else { WAITN(0); }
    SB0();
    const int bk = j & 1;
#pragma unroll
    for (int ks = 0; ks < 2; ++ks)
#pragma unroll
      for (int m = 0; m < 4; ++m) {
        acc[m][0] = MFMA16(Ab[bk][m * 2 + ks], Wb[bk][ks], acc[m][0]);
        acc[m][1] = MFMA16(Ab[bk][m * 2 + ks], Wb[bk][2 + ks], acc[m][1]);
      }
    SB0();
    if (j + 2 < Q) ISSUE(c0 + j + 2, bk);
    SB0();
  }
#undef ISSUE
#undef LDU
}

__global__ void __launch_bounds__(256)
k_lstm(const ushort_t* __restrict__ xb,
       const ushort_t* __restrict__ Wp,
       const float* __restrict__ b0,
       const float* __restrict__ bL,
       ushort_t* __restrict__ hbf,   // [2][L][LSLOT] packed bf16, pre-zeroed
       float* __restrict__ out, int multi) {
  cooperative_groups::grid_group grid = cooperative_groups::this_grid();
  float* __restrict__ seq = out;                           // [B][S][H]
  float* __restrict__ hf = out + (size_t)B_ * S_ * H_;     // [L][B][H]
  float* __restrict__ cf = hf + (size_t)L_ * B_ * H_;      // [L][B][H]
  __shared__ float zsp[4][64][33];   // per-wave K-partials (padded)
  __shared__ float hstF[512];        // h staging: [row][8 cols]

  const int tid = threadIdx.x;
  const int w = tid >> 6;        // wave = K-quarter
  const int lane = tid & 63;
  const int l15 = lane & 15;
  const int kg = lane >> 4;
  const int wg = blockIdx.x;
  const int nwg = gridDim.x;

  // gate-phase identity: thread owns (row, 2 H-cols), fixed per task
  const int grow = tid >> 2;
  const int gq = (tid & 3) << 1;    // hcl0: 0,2,4,6
  float creg[2] = {0.f, 0.f};

  for (int T = 0; T < NTICK; ++T) {
    for (int task = wg; task < NTASK; task += nwg) {
      const int l = task >> 7;
      const int jb = task & 127;
      const int t = T - l;
      if (t < 0 || t >= S_) continue;
      const ushort_t* __restrict__ hprev = hbf + (size_t)((T + 1) & 1) * (L_ * LSLOT);
      ushort_t* __restrict__ hcur = hbf + (size_t)(T & 1) * (L_ * LSLOT) + (size_t)l * LSLOT;
      const ushort_t* __restrict__ panel = Wp + poff(l, jb);
      const ushort_t* __restrict__ A2 = hprev + (size_t)l * LSLOT;

      f32x4 acc[4][2];
#pragma unroll
      for (int m = 0; m < 4; ++m) {
        acc[m][0] = (f32x4){0.f, 0.f, 0.f, 0.f};
        acc[m][1] = (f32x4){0.f, 0.f, 0.f, 0.f};
      }
      if (l == 0)
        gemm_q<24>(acc, panel, xb + (size_t)t * XSLOT, A2, w, lane);
      else
        gemm_q<32>(acc, panel, hprev + (size_t)(l - 1) * LSLOT, A2, w, lane);

      // write partials: row = m*16 + kg*4 + j, col32 = nf*16 + l15
#pragma unroll
      for (int m = 0; m < 4; ++m)
#pragma unroll
        for (int nf = 0; nf < 2; ++nf)
#pragma unroll
          for (int j = 0; j < 4; ++j)
            zsp[w][m * 16 + kg * 4 + j][nf * 16 + l15] = acc[m][nf][j];
      __syncthreads();

      // ---- gate phase: thread = (row, 2 cols); sum 4 K-partials ----
      {
        const int hc0 = (jb << 3) + gq;
        const float* __restrict__ bias = (l == 0) ? b0 : (bL + (size_t)(l - 1) * NG_);
        const size_t cbase = ((size_t)l * B_ + grow) * H_ + hc0;
        f32x2 cold;
        if (multi) {
          if (t > 0) cold = *(const f32x2*)(cf + cbase);
          else cold = (f32x2){0.f, 0.f};
        } else {
          cold = (f32x2){creg[0], creg[1]};
        }
        f32x2 hv2, cn2;
#pragma unroll
        for (int q = 0; q < 2; ++q) {
          const int hcl = gq + q;
          float z[4];
#pragma unroll
          for (int g = 0; g < 4; ++g) {
            const int c32 = (g >> 1) * 16 + (g & 1) * 8 + hcl;
            z[g] = zsp[0][grow][c32] + zsp[1][grow][c32] +
                   zsp[2][grow][c32] + zsp[3][grow][c32] +
                   bias[g * 1024 + hc0 + q];
          }
          float iv = 1.f / (1.f + expf(-z[0]));
          float fv = 1.f / (1.f + expf(-z[1]));
          float gv = tanhf(z[2]);
          float ov = 1.f / (1.f + expf(-z[3]));
          float cn = fv * cold[q] + iv * gv;
          cn2[q] = cn;
          creg[q] = cn;
          float hv = ov * tanhf(cn);
          hv2[q] = hv;
          hstF[grow * 8 + hcl] = hv;
        }
        if (multi || t == S_ - 1) *(f32x2*)(cf + cbase) = cn2;
        if (t == S_ - 1) *(f32x2*)(hf + cbase) = hv2;
        if (l == L_ - 1)
          *(f32x2*)(seq + ((size_t)grow * S_ + t) * H_ + hc0) = hv2;
      }
      __syncthreads();

      // ---- h write in packed-A unit order (unit = c*8 + m*2 + ks) ----
      if (tid < 64) {
        const int m = tid >> 4, lr = tid & 15;
        const float* hp = &hstF[(m * 16 + lr) * 8];
        ushort8v u8 = { f2bf(hp[0]), f2bf(hp[1]), f2bf(hp[2]), f2bf(hp[3]),
                        f2bf(hp[4]), f2bf(hp[5]), f2bf(hp[6]), f2bf(hp[7]) };
        *(ushort8v*)(hcur +
                     (((size_t)(jb >> 3) * 8 + m * 2 + ((jb >> 2) & 1)) * 64 +
                      ((jb & 3) * 16 + lr)) * 8) = u8;
      }
      __syncthreads();               // zsp/hstF safe before next task
    }
    grid.sync();
  }
}

extern "C" void kernel_launch(void* const* d_in, const int* in_sizes, int n_in,
                              void* d_out, int out_size, void* d_ws, size_t ws_size,
                              hipStream_t stream) {
  const float* x = (const float*)d_in[0];
  const float* U0 = (const float*)d_in[1];
  const float* V0 = (const float*)d_in[2];
  const float* b0 = (const float*)d_in[3];
  const float* U = (const float*)d_in[4];
  const float* V = (const float*)d_in[5];
  const float* bL = (const float*)d_in[6];
  float* out = (float*)d_out;

  char* ws = (char*)d_ws;
  unsigned short* Wp = (unsigned short*)ws;
  unsigned short* xb = (unsigned short*)(ws + WP_BYTES);
  unsigned short* hbf = (unsigned short*)(ws + WP_BYTES + XB_BYTES);

  hipLaunchKernelGGL(k_pack_w, dim3(NTASK), dim3(256), 0, stream, U0, V0, U, V, Wp);
  hipLaunchKernelGGL(k_cvt_x, dim3(S_), dim3(256), 0, stream, x, xb);
  hipMemsetAsync(hbf, 0, HBF_ELEMS * 2, stream);

  int maxB = 0;
  hipOccupancyMaxActiveBlocksPerMultiprocessor(&maxB, k_lstm, 256, 0);
  int nwg = maxB * 256;
  if (nwg > NTASK) nwg = NTASK;
  if (nwg < 64) nwg = 64;
  int multi = (nwg < NTASK) ? 1 : 0;

  void* args[] = { (void*)&xb, (void*)&Wp, (void*)&b0, (void*)&bL,
                   (void*)&hbf, (void*)&out, (void*)&multi };
  hipError_t e = hipLaunchCooperativeKernel((void*)k_lstm, dim3(nwg), dim3(256),
                                            args, 0, stream);
  if (e != hipSuccess) {
    (void)hipGetLastError();
    nwg = 256; multi = 1;
    void* args2[] = { (void*)&xb, (void*)&Wp, (void*)&b0, (void*)&bL,
                      (void*)&hbf, (void*)&out, (void*)&multi };
    hipLaunchCooperativeKernel((void*)k_lstm, dim3(nwg), dim3(256),
                               args2, 0, stream);
  }
}